// Round 6
// baseline (470.969 us; speedup 1.0000x reference)
//
#include <hip/hip_runtime.h>
#include <hip/hip_bf16.h>

#define NN 4096
#define IN_F 256
#define OUT_F 128
#define ALPHA 0.2f

typedef __bf16 bf16x8 __attribute__((ext_vector_type(8)));
typedef float f32x4 __attribute__((ext_vector_type(4)));
typedef float f32x16 __attribute__((ext_vector_type(16)));

__device__ __forceinline__ float bf2f(unsigned short u) {
  return __uint_as_float(((unsigned int)u) << 16);
}
__device__ __forceinline__ unsigned short f2bf(float f) {
  union { float f; unsigned int u; } x; x.f = f;
  unsigned int r = x.u + 0x7FFF + ((x.u >> 16) & 1);
  return (unsigned short)(r >> 16);
}
// 8 bits -> 8 bf16 values in {0.0, 1.0}; bit j -> element j
__device__ __forceinline__ bf16x8 bits2bf8(unsigned int b) {
  union { unsigned int u[4]; bf16x8 v; } o;
  #pragma unroll
  for (int e = 0; e < 4; ++e) {
    unsigned int lo = (b >> (2 * e)) & 1u;
    unsigned int hi = (b >> (2 * e + 1)) & 1u;
    o.u[e] = lo * 0x3F80u + hi * 0x3F800000u;
  }
  return o.v;
}

// ---- converts ----
__global__ __launch_bounds__(256) void k_cvt_h(const float* __restrict__ h,
                                               unsigned short* __restrict__ hb) {
  int idx = (blockIdx.x * 256 + threadIdx.x) * 8;
  float4 v0 = *(const float4*)(h + idx);
  float4 v1 = *(const float4*)(h + idx + 4);
  union { unsigned short u[8]; uint4 q; } o;
  o.u[0] = f2bf(v0.x); o.u[1] = f2bf(v0.y); o.u[2] = f2bf(v0.z); o.u[3] = f2bf(v0.w);
  o.u[4] = f2bf(v1.x); o.u[5] = f2bf(v1.y); o.u[6] = f2bf(v1.z); o.u[7] = f2bf(v1.w);
  *(uint4*)(hb + idx) = o.q;
}

__global__ __launch_bounds__(256) void k_cvt_w(const float* __restrict__ W,
                                               unsigned short* __restrict__ Wtb) {
  const int i = blockIdx.y;
  const int k0 = blockIdx.x * 32;
  const int t = threadIdx.x;
  __shared__ float tile[32][129];
  #pragma unroll
  for (int j = 0; j < 16; ++j) {
    int idx = t + j * 256;
    int r = idx >> 7, c = idx & 127;
    tile[r][c] = W[(size_t)(i * IN_F + k0 + r) * OUT_F + c];
  }
  __syncthreads();
  const int c = t >> 1, half = t & 1;
  unsigned short* dst = Wtb + ((size_t)i * OUT_F + c) * IN_F + k0 + half * 16;
  #pragma unroll
  for (int g = 0; g < 4; ++g) {
    ushort4 v;
    v.x = f2bf(tile[half * 16 + g * 4 + 0][c]);
    v.y = f2bf(tile[half * 16 + g * 4 + 1][c]);
    v.z = f2bf(tile[half * 16 + g * 4 + 2][c]);
    v.w = f2bf(tile[half * 16 + g * 4 + 3][c]);
    *(ushort4*)(dst + g * 4) = v;
  }
}

// ---- K1: Whnewf[i] = h @ W_i (MFMA) + Wh1/Wh2 vectors ----
__global__ __launch_bounds__(256) void k_front(const unsigned short* __restrict__ hb,
                                               const unsigned short* __restrict__ Wtb,
                                               const float* __restrict__ a,
                                               float* __restrict__ Whnewf,
                                               float* __restrict__ Wh1,
                                               float* __restrict__ Wh2) {
  const int i = blockIdx.y;
  const int r0 = blockIdx.x * 32;
  const int t = threadIdx.x;
  const int lane = t & 63, wid = t >> 6;
  const int m = wid & 1, nh = wid >> 1, nbase = nh * 64;
  const int ln = lane & 15, lk = lane >> 4;

  __shared__ float a1s[128], a2s[128];
  __shared__ float red1[2][32], red2[2][32];

  if (t < 128) {
    a1s[t] = a[(size_t)2 * i * OUT_F + t];
    a2s[t] = a[(size_t)(2 * i + 1) * OUT_F + t];
  }
  __syncthreads();

  const unsigned short* ap = hb + (size_t)(r0 + m * 16 + ln) * IN_F + lk * 8;
  const unsigned short* bp = Wtb + ((size_t)i * OUT_F + nbase + ln) * IN_F + lk * 8;

  f32x4 z4 = {0.f, 0.f, 0.f, 0.f};
  f32x4 acc[4] = {z4, z4, z4, z4};
  #pragma unroll
  for (int ks = 0; ks < 8; ++ks) {
    bf16x8 av = *(const bf16x8*)(ap + ks * 32);
    acc[0] = __builtin_amdgcn_mfma_f32_16x16x32_bf16(av, *(const bf16x8*)(bp + 0 * 16 * IN_F + ks * 32), acc[0], 0, 0, 0);
    acc[1] = __builtin_amdgcn_mfma_f32_16x16x32_bf16(av, *(const bf16x8*)(bp + 1 * 16 * IN_F + ks * 32), acc[1], 0, 0, 0);
    acc[2] = __builtin_amdgcn_mfma_f32_16x16x32_bf16(av, *(const bf16x8*)(bp + 2 * 16 * IN_F + ks * 32), acc[2], 0, 0, 0);
    acc[3] = __builtin_amdgcn_mfma_f32_16x16x32_bf16(av, *(const bf16x8*)(bp + 3 * 16 * IN_F + ks * 32), acc[3], 0, 0, 0);
  }

  float d1[4] = {0.f, 0.f, 0.f, 0.f}, d2[4] = {0.f, 0.f, 0.f, 0.f};
  #pragma unroll
  for (int f = 0; f < 4; ++f) {
    const int col = nbase + f * 16 + ln;
    const float va1 = a1s[col], va2 = a2s[col];
    #pragma unroll
    for (int q = 0; q < 4; ++q) {
      const int row = m * 16 + lk * 4 + q;
      const float v = acc[f][q];
      Whnewf[((size_t)i * NN + r0 + row) * OUT_F + col] = v;
      d1[q] += v * va1;
      d2[q] += v * va2;
    }
  }
  #pragma unroll
  for (int msk = 1; msk < 16; msk <<= 1) {
    #pragma unroll
    for (int q = 0; q < 4; ++q) {
      d1[q] += __shfl_xor(d1[q], msk, 64);
      d2[q] += __shfl_xor(d2[q], msk, 64);
    }
  }
  if (ln == 0) {
    #pragma unroll
    for (int q = 0; q < 4; ++q) {
      red1[nh][m * 16 + lk * 4 + q] = d1[q];
      red2[nh][m * 16 + lk * 4 + q] = d2[q];
    }
  }
  __syncthreads();
  if (t < 32) {
    Wh1[(size_t)i * NN + r0 + t] = red1[0][t] + red1[1][t];
    Wh2[(size_t)i * NN + r0 + t] = red2[0][t] + red2[1][t];
  }
}

// ---- gmax2[i] = max_c Wh2[i][c] ----
__global__ __launch_bounds__(256) void k_gmax(const float* __restrict__ Wh2,
                                              float* __restrict__ gmax2) {
  const int i = blockIdx.x;
  const int t = threadIdx.x;
  __shared__ float red[4];
  float m = -3.0e38f;
  #pragma unroll
  for (int j = 0; j < 16; ++j) m = fmaxf(m, Wh2[(size_t)i * NN + t + j * 256]);
  #pragma unroll
  for (int o = 32; o > 0; o >>= 1) m = fmaxf(m, __shfl_down(m, o, 64));
  if ((t & 63) == 0) red[t >> 6] = m;
  __syncthreads();
  if (t == 0) gmax2[i] = fmaxf(fmaxf(red[0], red[1]), fmaxf(red[2], red[3]));
}

// ---- per-col e^{w2}, e^{a w2} (bf16) and per-row fp/fm factors ----
__global__ __launch_bounds__(256) void k_prep(const float* __restrict__ Wh1,
                                              const float* __restrict__ Wh2,
                                              const float* __restrict__ gmax2,
                                              unsigned short* __restrict__ ew2pb,
                                              unsigned short* __restrict__ ew2mb,
                                              float* __restrict__ fpv,
                                              float* __restrict__ fmv) {
  int id = blockIdx.x * 256 + threadIdx.x;   // 3*NN
  float w2 = Wh2[id];
  ew2pb[id] = f2bf(__expf(w2));
  ew2mb[id] = f2bf(__expf(ALPHA * w2));
  float w1 = Wh1[id];
  float gi = gmax2[id >> 12];
  float e0 = w1 + gi;
  float mx = (e0 > 0.f) ? e0 : ALPHA * e0;
  fpv[id] = __expf(w1 - mx);
  fmv[id] = __expf(ALPHA * w1 - mx);
}

// ---- Vkm[i][s][n][c] = bf16( e~[s][c] * Whnewf[i][c][n] ), k-major ----
__global__ __launch_bounds__(256) void k_scale(const float* __restrict__ Whnewf,
                                               const unsigned short* __restrict__ ew2pb,
                                               const unsigned short* __restrict__ ew2mb,
                                               unsigned short* __restrict__ Vkm) {
  const int i = blockIdx.y;
  const int k0 = blockIdx.x * 32;
  const int t = threadIdx.x;
  __shared__ float tile[32][129];
  __shared__ float ewsp[32], ewsm[32];
  if (t < 32) {
    ewsp[t] = bf2f(ew2pb[(size_t)i * NN + k0 + t]);
    ewsm[t] = bf2f(ew2mb[(size_t)i * NN + k0 + t]);
  }
  #pragma unroll
  for (int j = 0; j < 16; ++j) {
    int idx = t + j * 256;
    int r = idx >> 7, c = idx & 127;
    tile[r][c] = Whnewf[((size_t)i * NN + k0 + r) * OUT_F + c];
  }
  __syncthreads();
  const int n = t >> 1, half = t & 1;
  unsigned short* dstP = Vkm + ((size_t)(i * 2 + 0) * OUT_F + n) * NN + k0 + half * 16;
  unsigned short* dstM = Vkm + ((size_t)(i * 2 + 1) * OUT_F + n) * NN + k0 + half * 16;
  #pragma unroll
  for (int g = 0; g < 4; ++g) {
    ushort4 vp, vm;
    float x0 = tile[half * 16 + g * 4 + 0][n];
    float x1 = tile[half * 16 + g * 4 + 1][n];
    float x2 = tile[half * 16 + g * 4 + 2][n];
    float x3 = tile[half * 16 + g * 4 + 3][n];
    vp.x = f2bf(ewsp[half * 16 + g * 4 + 0] * x0);
    vp.y = f2bf(ewsp[half * 16 + g * 4 + 1] * x1);
    vp.z = f2bf(ewsp[half * 16 + g * 4 + 2] * x2);
    vp.w = f2bf(ewsp[half * 16 + g * 4 + 3] * x3);
    vm.x = f2bf(ewsm[half * 16 + g * 4 + 0] * x0);
    vm.y = f2bf(ewsm[half * 16 + g * 4 + 1] * x1);
    vm.z = f2bf(ewsm[half * 16 + g * 4 + 2] * x2);
    vm.w = f2bf(ewsm[half * 16 + g * 4 + 3] * x3);
    *(ushort4*)(dstP + g * 4) = vp;
    *(ushort4*)(dstM + g * 4) = vm;
  }
}

// ---- PASS 1: pure mask stream -> 2-bit matrices. One block-iter = one row.
// No shuffles, no LDS, no sums. grid 3072, 4 rows per block (grid-stride). ----
__global__ __launch_bounds__(256) void k_bits(const int* __restrict__ mask,
                                              const float* __restrict__ Wh1,
                                              const float* __restrict__ Wh2,
                                              unsigned int* __restrict__ Bits) {
  const int t = threadIdx.x;
  for (int row = blockIdx.x; row < 3 * NN; row += 3072) {  // row = i*NN + r
    const float w1 = Wh1[row];
    const float* w2row = Wh2 + (row & ~(NN - 1));
    const int* mrow = mask + (size_t)row * NN + t * 16;
    unsigned int bp = 0, bm = 0;
    #pragma unroll
    for (int g = 0; g < 4; ++g) {
      int4 mv = *(const int4*)(mrow + g * 4);
      float4 w2 = *(const float4*)(w2row + t * 16 + g * 4);
      bool c0 = w1 + w2.x > 0.f, c1 = w1 + w2.y > 0.f;
      bool c2 = w1 + w2.z > 0.f, c3 = w1 + w2.w > 0.f;
      if (mv.x > 0) { if (c0) bp |= 1u << (g * 4 + 0); else bm |= 1u << (g * 4 + 0); }
      if (mv.y > 0) { if (c1) bp |= 1u << (g * 4 + 1); else bm |= 1u << (g * 4 + 1); }
      if (mv.z > 0) { if (c2) bp |= 1u << (g * 4 + 2); else bm |= 1u << (g * 4 + 2); }
      if (mv.w > 0) { if (c3) bp |= 1u << (g * 4 + 3); else bm |= 1u << (g * 4 + 3); }
    }
    Bits[(size_t)row * 256 + t] = bp | (bm << 16);
  }
}

// ---- PASS 2: Upart[z] = fp*(P+ @ V+) + fm*(P- @ V-) via 32x32x16 MFMA.
// No LDS, no barriers, no atomics. B-frags direct from L2-resident Vkm.
// Row sums via broadcast e^{w2} B-frag (nh0: P-sum, nh1: M-sum).
// grid (64,3,4) XCD-swizzled; block = 4 waves (m x nh), 64 rows x 128 n x 1024 k. ----
__global__ __launch_bounds__(256) void k_attn2(const unsigned short* __restrict__ Vkm,
                                               const unsigned int* __restrict__ Bits,
                                               const unsigned short* __restrict__ ew2pb,
                                               const unsigned short* __restrict__ ew2mb,
                                               const float* __restrict__ fpv,
                                               const float* __restrict__ fmv,
                                               float* __restrict__ Upart,
                                               float* __restrict__ SPp,
                                               float* __restrict__ SMp) {
  // bijective XCD swizzle: 768 blocks, 96 consecutive work-items per XCD
  const unsigned int lid = blockIdx.x + 64u * (blockIdx.y + 3u * blockIdx.z);
  const unsigned int swz = (lid & 7u) * 96u + (lid >> 3);
  const int bx = swz & 63;          // row tile (64 rows)
  const int w = swz >> 6;           // 0..11
  const int i = w % 3;
  const int z = w / 3;

  const int r0 = bx * 64;
  const int cb = z * 1024;
  const int t = threadIdx.x, lane = t & 63, wid = t >> 6;
  const int m = wid & 1, nh = wid >> 1;
  const int l31 = lane & 31, kh = lane >> 5;
  const int n0 = nh * 64 + l31, n1 = n0 + 32;

  const unsigned int* brow = Bits + ((size_t)i * NN + r0 + m * 32 + l31) * 256 + (cb >> 4);
  const unsigned short* vP0 = Vkm + ((size_t)(i * 2 + 0) * OUT_F + n0) * NN + cb + kh * 8;
  const unsigned short* vP1 = Vkm + ((size_t)(i * 2 + 0) * OUT_F + n1) * NN + cb + kh * 8;
  const unsigned short* vM0 = Vkm + ((size_t)(i * 2 + 1) * OUT_F + n0) * NN + cb + kh * 8;
  const unsigned short* vM1 = Vkm + ((size_t)(i * 2 + 1) * OUT_F + n1) * NN + cb + kh * 8;
  const unsigned short* eB = (nh == 0 ? ew2pb : ew2mb) + (size_t)i * NN + cb + kh * 8;

  f32x16 accP0 = {}, accP1 = {}, accM0 = {}, accM1 = {}, accS = {};

  #pragma unroll 2
  for (int chunk = 0; chunk < 16; ++chunk) {
    uint4 wv4 = *(const uint4*)(brow + chunk * 4);
    unsigned int wv[4] = {wv4.x, wv4.y, wv4.z, wv4.w};
    #pragma unroll
    for (int kst = 0; kst < 4; ++kst) {
      const int ko = chunk * 64 + kst * 16;
      unsigned int sh = wv[kst] >> (kh * 8);
      bf16x8 aP = bits2bf8(sh & 0xFFu);
      bf16x8 aM = bits2bf8((sh >> 16) & 0xFFu);
      bf16x8 bP0 = *(const bf16x8*)(vP0 + ko);
      bf16x8 bP1 = *(const bf16x8*)(vP1 + ko);
      bf16x8 bM0 = *(const bf16x8*)(vM0 + ko);
      bf16x8 bM1 = *(const bf16x8*)(vM1 + ko);
      bf16x8 eF  = *(const bf16x8*)(eB + ko);
      accP0 = __builtin_amdgcn_mfma_f32_32x32x16_bf16(aP, bP0, accP0, 0, 0, 0);
      accP1 = __builtin_amdgcn_mfma_f32_32x32x16_bf16(aP, bP1, accP1, 0, 0, 0);
      accM0 = __builtin_amdgcn_mfma_f32_32x32x16_bf16(aM, bM0, accM0, 0, 0, 0);
      accM1 = __builtin_amdgcn_mfma_f32_32x32x16_bf16(aM, bM1, accM1, 0, 0, 0);
      accS  = __builtin_amdgcn_mfma_f32_32x32x16_bf16(nh == 0 ? aP : aM, eF, accS, 0, 0, 0);
    }
  }

  const int rbase = r0 + m * 32;
  #pragma unroll
  for (int q = 0; q < 16; ++q) {
    const int crow = (q & 3) + 8 * (q >> 2) + 4 * kh;
    const int r = rbase + crow;
    const float fp = fpv[(size_t)i * NN + r];
    const float fm = fmv[(size_t)i * NN + r];
    float* urow = Upart + ((size_t)(z * 3 + i) * NN + r) * OUT_F;
    urow[n0] = fp * accP0[q] + fm * accM0[q];
    urow[n1] = fp * accP1[q] + fm * accM1[q];
  }
  if (l31 == 0) {
    #pragma unroll
    for (int q = 0; q < 16; ++q) {
      const int r = rbase + (q & 3) + 8 * (q >> 2) + 4 * kh;
      if (nh == 0) SPp[(size_t)(z * 3 + i) * NN + r] = accS[q];
      else         SMp[(size_t)(z * 3 + i) * NN + r] = accS[q];
    }
  }
}

// ---- final: out = elu( sum_i coef_i * (Σz Up)/(fp ΣzSP + fm ΣzSM) + 0.125*Whnew2 ) ----
__global__ __launch_bounds__(256) void k_final(const float* __restrict__ Upart,
                                               const float* __restrict__ SPp,
                                               const float* __restrict__ SMp,
                                               const float* __restrict__ fpv,
                                               const float* __restrict__ fmv,
                                               const float* __restrict__ Whnewf,
                                               float* __restrict__ out) {
  int idx = blockIdx.x * 256 + threadIdx.x;
  int r = idx >> 7;
  float v = 0.125f * Whnewf[(size_t)2 * NN * OUT_F + idx];
  #pragma unroll
  for (int i = 0; i < 3; ++i) {
    const float coef = (i == 0) ? 0.5f : (i == 1) ? 0.25f : 0.125f;
    float u = 0.f, sp = 0.f, sm = 0.f;
    #pragma unroll
    for (int zz = 0; zz < 4; ++zz) {
      u  += Upart[((size_t)(zz * 3 + i) * NN) * OUT_F + idx];
      sp += SPp[(size_t)(zz * 3 + i) * NN + r];
      sm += SMp[(size_t)(zz * 3 + i) * NN + r];
    }
    const float S = fpv[(size_t)i * NN + r] * sp + fmv[(size_t)i * NN + r] * sm;
    v += coef * u / S;
  }
  out[idx] = (v > 0.f) ? v : (__expf(v) - 1.0f);
}

extern "C" void kernel_launch(void* const* d_in, const int* in_sizes, int n_in,
                              void* d_out, int out_size, void* d_ws, size_t ws_size,
                              hipStream_t stream) {
  const float* h    = (const float*)d_in[0];
  const int*   mask = (const int*)d_in[1];
  const float* W    = (const float*)d_in[2];
  const float* a    = (const float*)d_in[3];
  float* out = (float*)d_out;

  float* Whnewf = (float*)d_ws;                        // 3*NN*128
  float* Wh1    = Whnewf + (size_t)3 * NN * OUT_F;     // 3*NN
  float* Wh2    = Wh1 + 3 * NN;                        // 3*NN
  float* gmax2  = Wh2 + 3 * NN;                        // 4
  float* fpv    = gmax2 + 4;                           // 3*NN
  float* fmv    = fpv + 3 * NN;                        // 3*NN
  float* Upart  = fmv + 3 * NN;                        // 4*3*NN*128
  float* SPp    = Upart + (size_t)4 * 3 * NN * OUT_F;  // 4*3*NN
  float* SMp    = SPp + 4 * 3 * NN;                    // 4*3*NN
  unsigned short* hb    = (unsigned short*)(SMp + 4 * 3 * NN);  // NN*256
  unsigned short* Wtb   = hb + (size_t)NN * IN_F;               // 3*128*256
  unsigned short* Vkm   = Wtb + (size_t)3 * OUT_F * IN_F;       // 3*2*128*NN
  unsigned short* ew2pb = Vkm + (size_t)3 * 2 * OUT_F * NN;     // 3*NN
  unsigned short* ew2mb = ew2pb + 3 * NN;                       // 3*NN
  unsigned int*   Bits  = (unsigned int*)(ew2mb + 3 * NN);      // 3*NN*256

  k_cvt_h<<<512, 256, 0, stream>>>(h, hb);
  k_cvt_w<<<dim3(8, 3), 256, 0, stream>>>(W, Wtb);
  k_front<<<dim3(128, 3), 256, 0, stream>>>(hb, Wtb, a, Whnewf, Wh1, Wh2);
  k_gmax<<<3, 256, 0, stream>>>(Wh2, gmax2);
  k_prep<<<48, 256, 0, stream>>>(Wh1, Wh2, gmax2, ew2pb, ew2mb, fpv, fmv);
  k_scale<<<dim3(128, 3), 256, 0, stream>>>(Whnewf, ew2pb, ew2mb, Vkm);
  k_bits<<<3072, 256, 0, stream>>>(mask, Wh1, Wh2, Bits);
  k_attn2<<<dim3(64, 3, 4), 256, 0, stream>>>(Vkm, Bits, ew2pb, ew2mb, fpv, fmv, Upart, SPp, SMp);
  k_final<<<(NN * OUT_F) / 256, 256, 0, stream>>>(Upart, SPp, SMp, fpv, fmv, Whnewf, out);
}

// Round 7
// 360.145 us; speedup vs baseline: 1.3077x; 1.3077x over previous
//
#include <hip/hip_runtime.h>
#include <hip/hip_bf16.h>

#define NN 4096
#define IN_F 256
#define OUT_F 128
#define ALPHA 0.2f

typedef __bf16 bf16x8 __attribute__((ext_vector_type(8)));
typedef float f32x4 __attribute__((ext_vector_type(4)));
typedef float f32x16 __attribute__((ext_vector_type(16)));

__device__ __forceinline__ float bf2f(unsigned short u) {
  return __uint_as_float(((unsigned int)u) << 16);
}
__device__ __forceinline__ unsigned short f2bf(float f) {
  union { float f; unsigned int u; } x; x.f = f;
  unsigned int r = x.u + 0x7FFF + ((x.u >> 16) & 1);
  return (unsigned short)(r >> 16);
}
// 8 bits -> 8 bf16 values in {0.0, 1.0}; bit j -> element j
__device__ __forceinline__ bf16x8 bits2bf8(unsigned int b) {
  union { unsigned int u[4]; bf16x8 v; } o;
  #pragma unroll
  for (int e = 0; e < 4; ++e) {
    unsigned int lo = (b >> (2 * e)) & 1u;
    unsigned int hi = (b >> (2 * e + 1)) & 1u;
    o.u[e] = lo * 0x3F80u + hi * 0x3F800000u;
  }
  return o.v;
}

// ---- Wtb[i][c][k] = bf16(W[i*256+k][c]) ----
__global__ __launch_bounds__(256) void k_cvt_w(const float* __restrict__ W,
                                               unsigned short* __restrict__ Wtb) {
  const int i = blockIdx.y;
  const int k0 = blockIdx.x * 32;
  const int t = threadIdx.x;
  __shared__ float tile[32][129];
  #pragma unroll
  for (int j = 0; j < 16; ++j) {
    int idx = t + j * 256;
    int r = idx >> 7, c = idx & 127;
    tile[r][c] = W[(size_t)(i * IN_F + k0 + r) * OUT_F + c];
  }
  __syncthreads();
  const int c = t >> 1, half = t & 1;
  unsigned short* dst = Wtb + ((size_t)i * OUT_F + c) * IN_F + k0 + half * 16;
  #pragma unroll
  for (int g = 0; g < 4; ++g) {
    ushort4 v;
    v.x = f2bf(tile[half * 16 + g * 4 + 0][c]);
    v.y = f2bf(tile[half * 16 + g * 4 + 1][c]);
    v.z = f2bf(tile[half * 16 + g * 4 + 2][c]);
    v.w = f2bf(tile[half * 16 + g * 4 + 3][c]);
    *(ushort4*)(dst + g * 4) = v;
  }
}

// ---- K1: Whnewf[i] = h @ W_i (MFMA, f32 h loads + in-reg cvt) + Wh1/Wh2 ----
__global__ __launch_bounds__(256) void k_front(const float* __restrict__ h,
                                               const unsigned short* __restrict__ Wtb,
                                               const float* __restrict__ a,
                                               float* __restrict__ Whnewf,
                                               float* __restrict__ Wh1,
                                               float* __restrict__ Wh2) {
  const int i = blockIdx.y;
  const int r0 = blockIdx.x * 32;
  const int t = threadIdx.x;
  const int lane = t & 63, wid = t >> 6;
  const int m = wid & 1, nh = wid >> 1, nbase = nh * 64;
  const int ln = lane & 15, lk = lane >> 4;

  __shared__ float a1s[128], a2s[128];
  __shared__ float red1[2][32], red2[2][32];

  if (t < 128) {
    a1s[t] = a[(size_t)2 * i * OUT_F + t];
    a2s[t] = a[(size_t)(2 * i + 1) * OUT_F + t];
  }
  __syncthreads();

  const float* ap = h + (size_t)(r0 + m * 16 + ln) * IN_F + lk * 8;
  const unsigned short* bp = Wtb + ((size_t)i * OUT_F + nbase + ln) * IN_F + lk * 8;

  f32x4 z4 = {0.f, 0.f, 0.f, 0.f};
  f32x4 acc[4] = {z4, z4, z4, z4};
  #pragma unroll
  for (int ks = 0; ks < 8; ++ks) {
    float4 h0 = *(const float4*)(ap + ks * 32);
    float4 h1 = *(const float4*)(ap + ks * 32 + 4);
    union { unsigned short u[8]; bf16x8 v; } av;
    av.u[0] = f2bf(h0.x); av.u[1] = f2bf(h0.y); av.u[2] = f2bf(h0.z); av.u[3] = f2bf(h0.w);
    av.u[4] = f2bf(h1.x); av.u[5] = f2bf(h1.y); av.u[6] = f2bf(h1.z); av.u[7] = f2bf(h1.w);
    acc[0] = __builtin_amdgcn_mfma_f32_16x16x32_bf16(av.v, *(const bf16x8*)(bp + 0 * 16 * IN_F + ks * 32), acc[0], 0, 0, 0);
    acc[1] = __builtin_amdgcn_mfma_f32_16x16x32_bf16(av.v, *(const bf16x8*)(bp + 1 * 16 * IN_F + ks * 32), acc[1], 0, 0, 0);
    acc[2] = __builtin_amdgcn_mfma_f32_16x16x32_bf16(av.v, *(const bf16x8*)(bp + 2 * 16 * IN_F + ks * 32), acc[2], 0, 0, 0);
    acc[3] = __builtin_amdgcn_mfma_f32_16x16x32_bf16(av.v, *(const bf16x8*)(bp + 3 * 16 * IN_F + ks * 32), acc[3], 0, 0, 0);
  }

  float d1[4] = {0.f, 0.f, 0.f, 0.f}, d2[4] = {0.f, 0.f, 0.f, 0.f};
  #pragma unroll
  for (int f = 0; f < 4; ++f) {
    const int col = nbase + f * 16 + ln;
    const float va1 = a1s[col], va2 = a2s[col];
    #pragma unroll
    for (int q = 0; q < 4; ++q) {
      const int row = m * 16 + lk * 4 + q;
      const float v = acc[f][q];
      Whnewf[((size_t)i * NN + r0 + row) * OUT_F + col] = v;
      d1[q] += v * va1;
      d2[q] += v * va2;
    }
  }
  #pragma unroll
  for (int msk = 1; msk < 16; msk <<= 1) {
    #pragma unroll
    for (int q = 0; q < 4; ++q) {
      d1[q] += __shfl_xor(d1[q], msk, 64);
      d2[q] += __shfl_xor(d2[q], msk, 64);
    }
  }
  if (ln == 0) {
    #pragma unroll
    for (int q = 0; q < 4; ++q) {
      red1[nh][m * 16 + lk * 4 + q] = d1[q];
      red2[nh][m * 16 + lk * 4 + q] = d2[q];
    }
  }
  __syncthreads();
  if (t < 32) {
    Wh1[(size_t)i * NN + r0 + t] = red1[0][t] + red1[1][t];
    Wh2[(size_t)i * NN + r0 + t] = red2[0][t] + red2[1][t];
  }
}

// ---- gmax + per-col e^{w2} (bf16) + per-row fp/fm. grid 3 (one block per hop). ----
__global__ __launch_bounds__(256) void k_gp(const float* __restrict__ Wh1,
                                            const float* __restrict__ Wh2,
                                            unsigned short* __restrict__ ew2pb,
                                            unsigned short* __restrict__ ew2mb,
                                            float* __restrict__ fpv,
                                            float* __restrict__ fmv) {
  const int i = blockIdx.x;
  const int t = threadIdx.x;
  __shared__ float red[4];
  __shared__ float gshared;
  float w2l[16];
  float m = -3.0e38f;
  #pragma unroll
  for (int j = 0; j < 16; ++j) {
    w2l[j] = Wh2[(size_t)i * NN + t + j * 256];
    m = fmaxf(m, w2l[j]);
  }
  #pragma unroll
  for (int o = 32; o > 0; o >>= 1) m = fmaxf(m, __shfl_down(m, o, 64));
  if ((t & 63) == 0) red[t >> 6] = m;
  __syncthreads();
  if (t == 0) gshared = fmaxf(fmaxf(red[0], red[1]), fmaxf(red[2], red[3]));
  __syncthreads();
  const float gi = gshared;
  #pragma unroll
  for (int j = 0; j < 16; ++j) {
    const int id = (int)((size_t)i * NN) + t + j * 256;
    ew2pb[id] = f2bf(__expf(w2l[j]));
    ew2mb[id] = f2bf(__expf(ALPHA * w2l[j]));
    float w1 = Wh1[id];
    float e0 = w1 + gi;
    float mx = (e0 > 0.f) ? e0 : ALPHA * e0;
    fpv[id] = __expf(w1 - mx);
    fmv[id] = __expf(ALPHA * w1 - mx);
  }
}

// ---- Vopt[i][s][kslab=c/16][n][c%16] = bf16( e~[s][c] * Whnewf[i][c][n] ).
// Fragment-order layout: a wave's B-frag load is one contiguous 1KB span. ----
__global__ __launch_bounds__(256) void k_scale(const float* __restrict__ Whnewf,
                                               const unsigned short* __restrict__ ew2pb,
                                               const unsigned short* __restrict__ ew2mb,
                                               unsigned short* __restrict__ Vopt) {
  const int i = blockIdx.y;
  const int k0 = blockIdx.x * 32;   // 32 graph-cols (c) per block
  const int t = threadIdx.x;
  __shared__ float tile[32][129];
  __shared__ float ewsp[32], ewsm[32];
  if (t < 32) {
    ewsp[t] = bf2f(ew2pb[(size_t)i * NN + k0 + t]);
    ewsm[t] = bf2f(ew2mb[(size_t)i * NN + k0 + t]);
  }
  #pragma unroll
  for (int j = 0; j < 16; ++j) {
    int idx = t + j * 256;
    int r = idx >> 7, c = idx & 127;
    tile[r][c] = Whnewf[((size_t)i * NN + k0 + r) * OUT_F + c];
  }
  __syncthreads();
  const int n = t & 127, ks = t >> 7;           // ks: which 16-c slab of the 32
  const int kslab = (k0 >> 4) + ks;
  #pragma unroll
  for (int s = 0; s < 2; ++s) {
    const float* ew = (s == 0) ? ewsp : ewsm;
    union { unsigned short u[16]; uint4 q[2]; } o;
    #pragma unroll
    for (int j = 0; j < 16; ++j) {
      const int cl = ks * 16 + j;
      o.u[j] = f2bf(ew[cl] * tile[cl][n]);
    }
    unsigned short* dst = Vopt + (((size_t)(i * 2 + s) * 256 + kslab) * 128 + n) * 16;
    *(uint4*)(dst) = o.q[0];
    *(uint4*)(dst + 8) = o.q[1];
  }
}

// ---- PASS 1: pure mask stream -> 2-bit matrices. grid 3072, 4 rows/block,
// w1/w2 hoisted to regs, ping-pong prefetch. ----
__global__ __launch_bounds__(256) void k_bits(const int* __restrict__ mask,
                                              const float* __restrict__ Wh1,
                                              const float* __restrict__ Wh2,
                                              unsigned int* __restrict__ Bits) {
  const int t = threadIdx.x;
  const int i = blockIdx.x >> 10;           // 1024 blocks per hop
  const int r0 = (blockIdx.x & 1023) * 4;
  float w2v[16];
  #pragma unroll
  for (int g = 0; g < 4; ++g) {
    float4 w2 = *(const float4*)(Wh2 + (size_t)i * NN + t * 16 + g * 4);
    w2v[g * 4 + 0] = w2.x; w2v[g * 4 + 1] = w2.y;
    w2v[g * 4 + 2] = w2.z; w2v[g * 4 + 3] = w2.w;
  }
  float w1v[4];
  #pragma unroll
  for (int rr = 0; rr < 4; ++rr) w1v[rr] = Wh1[(size_t)i * NN + r0 + rr];
  const int* mbase = mask + ((size_t)i * NN + r0) * NN + t * 16;
  int mA[16], mB[16];
  auto LD = [&](int rr, int* mv) {
    #pragma unroll
    for (int g = 0; g < 4; ++g) {
      int4 v = *(const int4*)(mbase + (size_t)rr * NN + g * 4);
      mv[g * 4 + 0] = v.x; mv[g * 4 + 1] = v.y;
      mv[g * 4 + 2] = v.z; mv[g * 4 + 3] = v.w;
    }
  };
  auto PR = [&](int rr, const int* mv) {
    const float w1 = w1v[rr];
    unsigned int bp = 0, bm = 0;
    #pragma unroll
    for (int j = 0; j < 16; ++j) {
      if (mv[j] > 0) {
        if (w1 + w2v[j] > 0.f) bp |= 1u << j; else bm |= 1u << j;
      }
    }
    Bits[((size_t)i * NN + r0 + rr) * 256 + t] = bp | (bm << 16);
  };
  LD(0, mA);
  LD(1, mB);
  PR(0, mA);
  LD(2, mA);
  PR(1, mB);
  LD(3, mB);
  PR(2, mA);
  PR(3, mB);
}

// ---- PASS 2: Upart[z] = fp*(P+ @ V+) + fm*(P- @ V-), 32x32x16 MFMA.
// No LDS, no barriers, no atomics; B-frags are contiguous 1KB wave-loads. ----
__global__ __launch_bounds__(256) void k_attn2(const unsigned short* __restrict__ Vopt,
                                               const unsigned int* __restrict__ Bits,
                                               const unsigned short* __restrict__ ew2pb,
                                               const unsigned short* __restrict__ ew2mb,
                                               const float* __restrict__ fpv,
                                               const float* __restrict__ fmv,
                                               float* __restrict__ Upart,
                                               float* __restrict__ SPp,
                                               float* __restrict__ SMp) {
  // bijective XCD swizzle: 768 blocks, 96 consecutive work-items per XCD
  const unsigned int lid = blockIdx.x + 64u * (blockIdx.y + 3u * blockIdx.z);
  const unsigned int swz = (lid & 7u) * 96u + (lid >> 3);
  const int bx = swz & 63;
  const int w = swz >> 6;
  const int i = w % 3;
  const int z = w / 3;

  const int r0 = bx * 64;
  const int cb = z * 1024;
  const int t = threadIdx.x, lane = t & 63, wid = t >> 6;
  const int m = wid & 1, nh = wid >> 1;
  const int l31 = lane & 31, kh = lane >> 5;
  const int n0 = nh * 64 + l31, n1 = n0 + 32;

  const unsigned int* brow = Bits + ((size_t)i * NN + r0 + m * 32 + l31) * 256 + (cb >> 4);
  // fragment-order V: per kslab advance = 128*16 elems = 2048
  const size_t fragoff = (size_t)nh * 1024 + l31 * 16 + kh * 8;
  const unsigned short* vP = Vopt + ((size_t)(i * 2 + 0) * 256 + (cb >> 4)) * 2048 + fragoff;
  const unsigned short* vM = Vopt + ((size_t)(i * 2 + 1) * 256 + (cb >> 4)) * 2048 + fragoff;
  const unsigned short* eB = (nh == 0 ? ew2pb : ew2mb) + (size_t)i * NN + cb + kh * 8;

  f32x16 accP0 = {}, accP1 = {}, accM0 = {}, accM1 = {}, accS = {};

  #pragma unroll 2
  for (int chunk = 0; chunk < 16; ++chunk) {
    uint4 wv4 = *(const uint4*)(brow + chunk * 4);
    unsigned int wv[4] = {wv4.x, wv4.y, wv4.z, wv4.w};
    #pragma unroll
    for (int kst = 0; kst < 4; ++kst) {
      const int kslab = chunk * 4 + kst;
      unsigned int sh = wv[kst] >> (kh * 8);
      bf16x8 aP = bits2bf8(sh & 0xFFu);
      bf16x8 aM = bits2bf8((sh >> 16) & 0xFFu);
      bf16x8 bP0 = *(const bf16x8*)(vP + (size_t)kslab * 2048);
      bf16x8 bP1 = *(const bf16x8*)(vP + (size_t)kslab * 2048 + 512);
      bf16x8 bM0 = *(const bf16x8*)(vM + (size_t)kslab * 2048);
      bf16x8 bM1 = *(const bf16x8*)(vM + (size_t)kslab * 2048 + 512);
      bf16x8 eF  = *(const bf16x8*)(eB + kslab * 16);
      accP0 = __builtin_amdgcn_mfma_f32_32x32x16_bf16(aP, bP0, accP0, 0, 0, 0);
      accP1 = __builtin_amdgcn_mfma_f32_32x32x16_bf16(aP, bP1, accP1, 0, 0, 0);
      accM0 = __builtin_amdgcn_mfma_f32_32x32x16_bf16(aM, bM0, accM0, 0, 0, 0);
      accM1 = __builtin_amdgcn_mfma_f32_32x32x16_bf16(aM, bM1, accM1, 0, 0, 0);
      accS  = __builtin_amdgcn_mfma_f32_32x32x16_bf16(nh == 0 ? aP : aM, eF, accS, 0, 0, 0);
    }
  }

  const int rbase = r0 + m * 32;
  #pragma unroll
  for (int q = 0; q < 16; ++q) {
    const int crow = (q & 3) + 8 * (q >> 2) + 4 * kh;
    const int r = rbase + crow;
    const float fp = fpv[(size_t)i * NN + r];
    const float fm = fmv[(size_t)i * NN + r];
    float* urow = Upart + ((size_t)(z * 3 + i) * NN + r) * OUT_F;
    urow[n0] = fp * accP0[q] + fm * accM0[q];
    urow[n1] = fp * accP1[q] + fm * accM1[q];
  }
  if (l31 == 0) {
    #pragma unroll
    for (int q = 0; q < 16; ++q) {
      const int r = rbase + (q & 3) + 8 * (q >> 2) + 4 * kh;
      if (nh == 0) SPp[(size_t)(z * 3 + i) * NN + r] = accS[q];
      else         SMp[(size_t)(z * 3 + i) * NN + r] = accS[q];
    }
  }
}

// ---- final: out = elu( sum_i coef_i * (Σz Up)/(fp ΣzSP + fm ΣzSM) + 0.125*Whnew2 ) ----
__global__ __launch_bounds__(256) void k_final(const float* __restrict__ Upart,
                                               const float* __restrict__ SPp,
                                               const float* __restrict__ SMp,
                                               const float* __restrict__ fpv,
                                               const float* __restrict__ fmv,
                                               const float* __restrict__ Whnewf,
                                               float* __restrict__ out) {
  int idx = blockIdx.x * 256 + threadIdx.x;
  int r = idx >> 7;
  float v = 0.125f * Whnewf[(size_t)2 * NN * OUT_F + idx];
  #pragma unroll
  for (int i = 0; i < 3; ++i) {
    const float coef = (i == 0) ? 0.5f : (i == 1) ? 0.25f : 0.125f;
    float u = 0.f, sp = 0.f, sm = 0.f;
    #pragma unroll
    for (int zz = 0; zz < 4; ++zz) {
      u  += Upart[((size_t)(zz * 3 + i) * NN) * OUT_F + idx];
      sp += SPp[(size_t)(zz * 3 + i) * NN + r];
      sm += SMp[(size_t)(zz * 3 + i) * NN + r];
    }
    const float S = fpv[(size_t)i * NN + r] * sp + fmv[(size_t)i * NN + r] * sm;
    v += coef * u / S;
  }
  out[idx] = (v > 0.f) ? v : (__expf(v) - 1.0f);
}

extern "C" void kernel_launch(void* const* d_in, const int* in_sizes, int n_in,
                              void* d_out, int out_size, void* d_ws, size_t ws_size,
                              hipStream_t stream) {
  const float* h    = (const float*)d_in[0];
  const int*   mask = (const int*)d_in[1];
  const float* W    = (const float*)d_in[2];
  const float* a    = (const float*)d_in[3];
  float* out = (float*)d_out;

  float* Whnewf = (float*)d_ws;                        // 3*NN*128
  float* Wh1    = Whnewf + (size_t)3 * NN * OUT_F;     // 3*NN
  float* Wh2    = Wh1 + 3 * NN;                        // 3*NN
  float* fpv    = Wh2 + 3 * NN;                        // 3*NN
  float* fmv    = fpv + 3 * NN;                        // 3*NN
  float* Upart  = fmv + 3 * NN;                        // 4*3*NN*128
  float* SPp    = Upart + (size_t)4 * 3 * NN * OUT_F;  // 4*3*NN
  float* SMp    = SPp + 4 * 3 * NN;                    // 4*3*NN
  unsigned short* Wtb   = (unsigned short*)(SMp + 4 * 3 * NN);  // 3*128*256
  unsigned short* Vopt  = Wtb + (size_t)3 * OUT_F * IN_F;       // 3*2*256*128*16
  unsigned short* ew2pb = Vopt + (size_t)3 * 2 * 256 * 128 * 16; // 3*NN
  unsigned short* ew2mb = ew2pb + 3 * NN;                        // 3*NN
  unsigned int*   Bits  = (unsigned int*)(ew2mb + 3 * NN);       // 3*NN*256

  k_cvt_w<<<dim3(8, 3), 256, 0, stream>>>(W, Wtb);
  k_front<<<dim3(128, 3), 256, 0, stream>>>(h, Wtb, a, Whnewf, Wh1, Wh2);
  k_gp<<<3, 256, 0, stream>>>(Wh1, Wh2, ew2pb, ew2mb, fpv, fmv);
  k_scale<<<dim3(128, 3), 256, 0, stream>>>(Whnewf, ew2pb, ew2mb, Vopt);
  k_bits<<<3072, 256, 0, stream>>>(mask, Wh1, Wh2, Bits);
  k_attn2<<<dim3(64, 3, 4), 256, 0, stream>>>(Vopt, Bits, ew2pb, ew2mb, fpv, fmv, Upart, SPp, SMp);
  k_final<<<(NN * OUT_F) / 256, 256, 0, stream>>>(Upart, SPp, SMp, fpv, fmv, Whnewf, out);
}